// Round 2
// baseline (336.906 us; speedup 1.0000x reference)
//
#include <hip/hip_runtime.h>
#include <hip/hip_bf16.h>
#include <stdint.h>

typedef __attribute__((ext_vector_type(8))) short bf16x8;
typedef __attribute__((ext_vector_type(4))) float f32x4;
typedef __attribute__((ext_vector_type(4))) unsigned short u16x4;

#define T_SEQ 2048
#define HID_D 2880
#define NH 64
#define NKV 8
#define HD 64
#define QKV_N 5120   // (64+16)*64
#define ATT_N 4096   // 64*64
#define WIN 128
#define RSCALE 0.125f          // D^-0.5
#define MSCALE 1.3465735903f   // 0.1*ln(32)+1

__device__ __forceinline__ unsigned short f2bf(float f) {
  union { float f; unsigned u; } v; v.f = f;
  unsigned r = v.u + 0x7fffu + ((v.u >> 16) & 1u);
  return (unsigned short)(r >> 16);
}

__device__ __forceinline__ void gload_lds16(const void* g, void* l) {
  __builtin_amdgcn_global_load_lds((const __attribute__((address_space(1))) char*)g,
                                   (__attribute__((address_space(3))) char*)l, 16, 0, 0);
}

// ---------------- RMSNorm -> bf16 ----------------
__global__ __launch_bounds__(256) void rmsnorm_kernel(const float* __restrict__ x,
                                                      const float* __restrict__ w,
                                                      unsigned short* __restrict__ t_bf) {
  int row = blockIdx.x;
  const float4* xr4 = (const float4*)(x + (size_t)row * HID_D);
  const float4* w4 = (const float4*)w;
  float ss = 0.f;
  for (int i = threadIdx.x; i < HID_D / 4; i += 256) {
    float4 v = xr4[i];
    ss += v.x * v.x + v.y * v.y + v.z * v.z + v.w * v.w;
  }
  __shared__ float red[256];
  red[threadIdx.x] = ss;
  __syncthreads();
  for (int s = 128; s > 0; s >>= 1) {
    if (threadIdx.x < s) red[threadIdx.x] += red[threadIdx.x + s];
    __syncthreads();
  }
  float rs = rsqrtf(red[0] / (float)HID_D + 1e-5f);
  u16x4* ob = (u16x4*)(t_bf + (size_t)row * HID_D);
  for (int i = threadIdx.x; i < HID_D / 4; i += 256) {
    float4 v = xr4[i];
    float4 g = w4[i];
    u16x4 o = { f2bf(v.x * rs * g.x), f2bf(v.y * rs * g.y),
                f2bf(v.z * rs * g.z), f2bf(v.w * rs * g.w) };
    ob[i] = o;
  }
}

// ---------------- fp32 -> bf16 (x4) ----------------
__global__ __launch_bounds__(256) void f2bf4_kernel(const float* __restrict__ in,
                                                    unsigned short* __restrict__ out, int n4) {
  int i = blockIdx.x * 256 + threadIdx.x;
  if (i >= n4) return;
  float4 v = ((const float4*)in)[i];
  u16x4 o = { f2bf(v.x), f2bf(v.y), f2bf(v.z), f2bf(v.w) };
  ((u16x4*)out)[i] = o;
}

// ---------------- GEMM: C[M,N] = A[M,K](bf16) * B[N,K]^T(bf16) + bias (+resid) ----------------
// 128x128 tile, BK=64, 4 waves (2x2), 16x16x32 bf16 MFMA. M%128==0, K%64==0. NCHECK guards N edge.
template <bool NCHECK, bool RESID>
__global__ __launch_bounds__(256) void gemm_bt(const unsigned short* __restrict__ A,
                                               const unsigned short* __restrict__ B,
                                               float* __restrict__ C,
                                               const float* __restrict__ bias,
                                               const float* __restrict__ resid,
                                               int M, int N, int K) {
  __shared__ unsigned short sA[128 * 64];
  __shared__ unsigned short sB[128 * 64];
  const int tid = threadIdx.x;
  const int lane = tid & 63, w = tid >> 6;
  const int wr = w >> 1, wc = w & 1;
  const int lq = lane & 15, ro = lane >> 4;
  const int m0 = blockIdx.y * 128, n0 = blockIdx.x * 128;
  const int srow = (tid * 8) >> 6;   // 0..31
  const int scol = (tid * 8) & 63;

  f32x4 acc[4][4] = {};

  for (int k0 = 0; k0 < K; k0 += 64) {
#pragma unroll
    for (int it = 0; it < 4; ++it) {
      int rr = it * 32 + srow;
      const unsigned short* ga = A + (size_t)(m0 + rr) * K + k0 + scol;
      gload_lds16(ga, &sA[it * 2048 + w * 512]);
      int bn = n0 + rr;
      if (NCHECK) bn = min(bn, N - 1);
      const unsigned short* gb = B + (size_t)bn * K + k0 + scol;
      gload_lds16(gb, &sB[it * 2048 + w * 512]);
    }
    __syncthreads();
#pragma unroll
    for (int kk = 0; kk < 2; ++kk) {
      bf16x8 a[4], b[4];
#pragma unroll
      for (int i = 0; i < 4; ++i)
        a[i] = *(const bf16x8*)&sA[(wr * 64 + i * 16 + lq) * 64 + kk * 32 + ro * 8];
#pragma unroll
      for (int j = 0; j < 4; ++j)
        b[j] = *(const bf16x8*)&sB[(wc * 64 + j * 16 + lq) * 64 + kk * 32 + ro * 8];
#pragma unroll
      for (int i = 0; i < 4; ++i)
#pragma unroll
        for (int j = 0; j < 4; ++j)
          acc[i][j] = __builtin_amdgcn_mfma_f32_16x16x32_bf16(a[i], b[j], acc[i][j], 0, 0, 0);
    }
    __syncthreads();
  }

#pragma unroll
  for (int i = 0; i < 4; ++i)
#pragma unroll
    for (int j = 0; j < 4; ++j) {
      int gr = m0 + wr * 64 + i * 16 + ro * 4;
      int gc = n0 + wc * 64 + j * 16 + lq;
      if (!NCHECK || gc < N) {
        float bv = bias[gc];
#pragma unroll
        for (int r = 0; r < 4; ++r) {
          size_t off = (size_t)(gr + r) * N + gc;
          float v = acc[i][j][r] + bv;
          if (RESID) v += resid[off];
          C[off] = v;
        }
      }
    }
}

// ---------------- YaRN RoPE (q & k) -> bf16 ----------------
__global__ __launch_bounds__(256) void rope_kernel(const float* __restrict__ qkv,
                                                   const int* __restrict__ positions,
                                                   unsigned short* __restrict__ qb,
                                                   unsigned short* __restrict__ kb) {
  int idx = blockIdx.x * 256 + threadIdx.x;
  const int total = T_SEQ * (NH + NKV) * 32;
  if (idx >= total) return;
  int d = idx & 31;
  int head = (idx >> 5) % (NH + NKV);
  int t = idx / ((NH + NKV) * 32);
  // inv_freq (low=8, high=18 from YaRN formula for these constants)
  float pw = (float)d * (1.0f / 32.0f);
  float extrap = expf(-pw * 11.9183905733f);  // THETA^-pw
  float interp = extrap * (1.0f / 32.0f);
  float ramp = fminf(fmaxf(((float)d - 8.0f) * 0.1f, 0.0f), 1.0f);
  float invf = interp * ramp + extrap * (1.0f - ramp);
  float fr = (float)positions[t] * invf;
  float s, c;
  sincosf(fr, &s, &c);
  c *= MSCALE;
  s *= MSCALE;
  if (head < NH) {
    const float* b = qkv + (size_t)t * QKV_N + head * HD + d;
    float x1 = b[0], x2 = b[32];
    unsigned short* ob = qb + (size_t)t * ATT_N + head * HD + d;
    ob[0] = f2bf(x1 * c - x2 * s);
    ob[32] = f2bf(x2 * c + x1 * s);
  } else {
    int gk = head - NH;
    const float* b = qkv + (size_t)t * QKV_N + NH * HD + gk * HD + d;
    float x1 = b[0], x2 = b[32];
    unsigned short* ob = kb + (size_t)t * (NKV * HD) + gk * HD + d;
    ob[0] = f2bf(x1 * c - x2 * s);
    ob[32] = f2bf(x2 * c + x1 * s);
  }
}

// ---------------- V transpose -> vt[g][d][t] bf16 ----------------
__global__ __launch_bounds__(256) void vtrans_kernel(const float* __restrict__ qkv,
                                                     unsigned short* __restrict__ vt) {
  int idx = blockIdx.x * 256 + threadIdx.x;  // (g*64+d)*2048 + t
  int t = idx & (T_SEQ - 1);
  int d = (idx >> 11) & 63;
  int g = idx >> 17;
  vt[idx] = f2bf(qkv[(size_t)t * QKV_N + (NH + NKV) * HD + g * HD + d]);
}

// ---------------- sliding-window attention with sinks ----------------
// One wave per (head, 16-q tile). S^T = K_tile * Q^T via 16x16x32 MFMA with a
// permuted key-row mapping so P lands directly in the PV A-fragment layout.
__global__ __launch_bounds__(256) void attn_kernel(const unsigned short* __restrict__ qb,
                                                   const unsigned short* __restrict__ kb,
                                                   const unsigned short* __restrict__ vt,
                                                   const float* __restrict__ sinks,
                                                   unsigned short* __restrict__ att) {
  const int lane = threadIdx.x & 63;
  const int wid = threadIdx.x >> 6;
  const int q0 = blockIdx.x * 16;
  const int h = blockIdx.y * 4 + wid;
  const int g = h >> 3;
  const int lq = lane & 15;
  const int ro = lane >> 4;

  bf16x8 bq0, bq1;
  {
    const unsigned short* qp = qb + (size_t)(q0 + lq) * ATT_N + h * HD + ro * 8;
    bq0 = *(const bf16x8*)qp;
    bq1 = *(const bf16x8*)(qp + 32);
  }
  float m_run = sinks[h];
  float l_run = 1.0f;
  f32x4 o0 = {0.f, 0.f, 0.f, 0.f}, o1 = o0, o2 = o0, o3 = o0;
  const int qg = q0 + lq;
  const int jstart = (q0 >= WIN) ? q0 - WIN : 0;

  for (int jt = jstart; jt <= q0; jt += 32) {
    f32x4 st0 = {0.f, 0.f, 0.f, 0.f}, st1 = st0;
    {
      // permuted key row for lane: tile0 -> jt + (lq/4)*8 + lq%4, tile1 -> +4
      int kr = jt + ((lq >> 2) << 3) + (lq & 3);
      int kr0 = min(kr, T_SEQ - 1);
      int kr1 = min(kr + 4, T_SEQ - 1);
      const unsigned short* kp0 = kb + (size_t)kr0 * (NKV * HD) + g * HD + ro * 8;
      const unsigned short* kp1 = kb + (size_t)kr1 * (NKV * HD) + g * HD + ro * 8;
      bf16x8 ka0a = *(const bf16x8*)kp0;
      bf16x8 ka0b = *(const bf16x8*)(kp0 + 32);
      bf16x8 ka1a = *(const bf16x8*)kp1;
      bf16x8 ka1b = *(const bf16x8*)(kp1 + 32);
      st0 = __builtin_amdgcn_mfma_f32_16x16x32_bf16(ka0a, bq0, st0, 0, 0, 0);
      st0 = __builtin_amdgcn_mfma_f32_16x16x32_bf16(ka0b, bq1, st0, 0, 0, 0);
      st1 = __builtin_amdgcn_mfma_f32_16x16x32_bf16(ka1a, bq0, st1, 0, 0, 0);
      st1 = __builtin_amdgcn_mfma_f32_16x16x32_bf16(ka1b, bq1, st1, 0, 0, 0);
    }
    // lane holds S[q=q0+lq][j = jt + ro*8 + r (+4 for tile1)]
    float p[8];
    float tmax = -3.0e30f;
#pragma unroll
    for (int r = 0; r < 4; ++r) {
      int jg0 = jt + ro * 8 + r;
      int jg1 = jg0 + 4;
      float s0 = (jg0 <= qg && (qg - jg0) < WIN) ? st0[r] * RSCALE : -3.0e30f;
      float s1 = (jg1 <= qg && (qg - jg1) < WIN) ? st1[r] * RSCALE : -3.0e30f;
      p[r] = s0;
      p[r + 4] = s1;
      tmax = fmaxf(tmax, fmaxf(s0, s1));
    }
    tmax = fmaxf(tmax, __shfl_xor(tmax, 16));
    tmax = fmaxf(tmax, __shfl_xor(tmax, 32));
    float m_new = fmaxf(m_run, tmax);
    float rescale = expf(m_run - m_new);   // factor for q-row lq
    float psum = 0.f;
    bf16x8 pa;
#pragma unroll
    for (int jj = 0; jj < 8; ++jj) {
      float pe = expf(p[jj] - m_new);
      psum += pe;
      pa[jj] = (short)f2bf(pe);
    }
    psum += __shfl_xor(psum, 16);
    psum += __shfl_xor(psum, 32);
    l_run = l_run * rescale + psum;
    m_run = m_new;
    // O accumulator rows are q-rows (ro*4 + r): fetch each row's rescale
    // factor from the lane holding it (lane s has row s's factor, s=0..15).
    f32x4 rs4;
#pragma unroll
    for (int r = 0; r < 4; ++r) rs4[r] = __shfl(rescale, ro * 4 + r);
    o0 *= rs4; o1 *= rs4; o2 *= rs4; o3 *= rs4;
    // V fragments: vt[g][d = dt*16+lq][t = jt + ro*8 + jj]
    int tb = jt + ro * 8;
    if (tb > T_SEQ - 8) tb = T_SEQ - 8;  // clamped rows are fully masked (p==0)
    const unsigned short* vp = vt + (size_t)(g * HD + lq) * T_SEQ + tb;
    bf16x8 v0 = *(const bf16x8*)vp;
    bf16x8 v1 = *(const bf16x8*)(vp + 16 * T_SEQ);
    bf16x8 v2 = *(const bf16x8*)(vp + 32 * T_SEQ);
    bf16x8 v3 = *(const bf16x8*)(vp + 48 * T_SEQ);
    o0 = __builtin_amdgcn_mfma_f32_16x16x32_bf16(pa, v0, o0, 0, 0, 0);
    o1 = __builtin_amdgcn_mfma_f32_16x16x32_bf16(pa, v1, o1, 0, 0, 0);
    o2 = __builtin_amdgcn_mfma_f32_16x16x32_bf16(pa, v2, o2, 0, 0, 0);
    o3 = __builtin_amdgcn_mfma_f32_16x16x32_bf16(pa, v3, o3, 0, 0, 0);
  }

#pragma unroll
  for (int r = 0; r < 4; ++r) {
    float lr = __shfl(l_run, ro * 4 + r);
    float inv = 1.0f / lr;
    int qrow = q0 + ro * 4 + r;
    unsigned short* op = att + (size_t)qrow * ATT_N + h * HD + lq;
    op[0] = f2bf(o0[r] * inv);
    op[16] = f2bf(o1[r] * inv);
    op[32] = f2bf(o2[r] * inv);
    op[48] = f2bf(o3[r] * inv);
  }
}

extern "C" void kernel_launch(void* const* d_in, const int* in_sizes, int n_in,
                              void* d_out, int out_size, void* d_ws, size_t ws_size,
                              hipStream_t stream) {
  const float* x = (const float*)d_in[0];
  const int* pos = (const int*)d_in[1];
  const float* norm_w = (const float*)d_in[2];
  const float* w_qkv = (const float*)d_in[3];
  const float* b_qkv = (const float*)d_in[4];
  const float* w_o = (const float*)d_in[5];
  const float* b_o = (const float*)d_in[6];
  const float* sinks = (const float*)d_in[7];
  float* out = (float*)d_out;

  // workspace layout (all 16B aligned)
  unsigned short* t_bf = (unsigned short*)d_ws;                    // [2048][2880]
  unsigned short* wq_bf = t_bf + (size_t)T_SEQ * HID_D;            // [5120][2880]
  unsigned short* wo_bf = wq_bf + (size_t)QKV_N * HID_D;           // [2880][4096]
  float* qkv = (float*)(wo_bf + (size_t)HID_D * ATT_N);            // [2048][5120] fp32
  unsigned short* qb = (unsigned short*)(qkv + (size_t)T_SEQ * QKV_N);  // [2048][4096]
  unsigned short* kb = qb + (size_t)T_SEQ * ATT_N;                 // [2048][512]
  unsigned short* vt = kb + (size_t)T_SEQ * NKV * HD;              // [8][64][2048]
  unsigned short* att = vt + (size_t)NKV * HD * T_SEQ;             // [2048][4096]

  rmsnorm_kernel<<<T_SEQ, 256, 0, stream>>>(x, norm_w, t_bf);
  f2bf4_kernel<<<(QKV_N * HID_D / 4 + 255) / 256, 256, 0, stream>>>(w_qkv, wq_bf, QKV_N * HID_D / 4);
  f2bf4_kernel<<<(HID_D * ATT_N / 4 + 255) / 256, 256, 0, stream>>>(w_o, wo_bf, HID_D * ATT_N / 4);
  gemm_bt<false, false><<<dim3(QKV_N / 128, T_SEQ / 128), 256, 0, stream>>>(
      t_bf, wq_bf, qkv, b_qkv, nullptr, T_SEQ, QKV_N, HID_D);
  rope_kernel<<<(T_SEQ * (NH + NKV) * 32 + 255) / 256, 256, 0, stream>>>(qkv, pos, qb, kb);
  vtrans_kernel<<<(NKV * HD * T_SEQ) / 256, 256, 0, stream>>>(qkv, vt);
  attn_kernel<<<dim3(T_SEQ / 16, NH / 4), 256, 0, stream>>>(qb, kb, vt, sinks, att);
  gemm_bt<true, true><<<dim3((HID_D + 127) / 128, T_SEQ / 128), 256, 0, stream>>>(
      att, wo_bf, out, b_o, x, T_SEQ, HID_D, ATT_N);
}